// Round 11
// baseline (185.266 us; speedup 1.0000x reference)
//
#include <hip/hip_runtime.h>

// WaveConv3d, reduced form:
//   s_k  = signed 4x4x4 block-reduce of x  (8 subbands, 16^3 per (b,c))
//   ih   = sparse 3D DFT of s_k (6x6x3 freqs)
//   oh   = per-frequency 64->64 channel mix
//   out  = x - mean_{2x2x2}(x) + (1/8) sum_k sign_k(cell) * idft(oh_k)
// Two-half pipeline for LLC residency: for half h in {0,1} (b-pairs):
//   K1(h): analyze + z/y-DFT on x[h] (134 MB, installs into LLC)
//   K2(h): in-LDS x-DFT + channel mix (w read NT — no LLC pollution)
//   K3(h): inverse DFT + synthesis; re-reads x[h] (LLC-resident), NT out.
// All kernel bodies are the R9-validated versions (R10's variants regressed).

typedef float f32x4 __attribute__((ext_vector_type(4)));

__constant__ float C16c[16] = {
  1.0f, 0.92387953251128675f, 0.70710678118654752f, 0.38268343236508977f,
  0.0f, -0.38268343236508977f, -0.70710678118654752f, -0.92387953251128675f,
  -1.0f, -0.92387953251128675f, -0.70710678118654752f, -0.38268343236508977f,
  0.0f, 0.38268343236508977f, 0.70710678118654752f, 0.92387953251128675f
};
__constant__ float S16c[16] = {
  0.0f, 0.38268343236508977f, 0.70710678118654752f, 0.92387953251128675f,
  1.0f, 0.92387953251128675f, 0.70710678118654752f, 0.38268343236508977f,
  0.0f, -0.38268343236508977f, -0.70710678118654752f, -0.92387953251128675f,
  -1.0f, -0.92387953251128675f, -0.70710678118654752f, -0.38268343236508977f
};
__constant__ int KYv[6] = {0, 1, 2, 13, 14, 15};

// ---------------------------------------------------------------------------
// K1: fused analyze + z-DFT + y-DFT for one b-half. WG = (bc_local, px).
// g2 layout: [b][row 144][px 16][c 64], row = k*18 + kyi*3 + kz.
__global__ __launch_bounds__(256) void k1_front(const float* __restrict__ x,
                                                float2* __restrict__ g2,
                                                int half) {
  __shared__ float sm[8 * 272 + 8];   // [k][py][pz(17)]
  __shared__ float2 fz[8 * 51];       // [k][kz][ny(17)]
  unsigned tid = threadIdx.x;
  unsigned px = blockIdx.x & 15u;
  unsigned bc = (unsigned)half * 128u + (blockIdx.x >> 4);
  unsigned c = bc & 63u, b = bc >> 6;
  const f32x4* xp4 = (const f32x4*)(x + ((size_t)bc << 18)) + (size_t)px * 4096u;
  unsigned z4 = tid & 15u;
#pragma unroll
  for (int q = 0; q < 4; q++) {
    float a00 = 0.f, a01 = 0.f, a10 = 0.f, a11 = 0.f;  // [dx][zhalf]
#pragma unroll
    for (int i = 0; i < 4; i++) {
      f32x4 v = xp4[i * 1024 + q * 256 + tid];
      float h0 = v.x + v.y, h1 = v.z + v.w;
      a00 += h0; a01 += h1;
      if (i < 2) { a10 += h0; a11 += h1; } else { a10 -= h0; a11 -= h1; }
    }
    float p00 = a00 + __shfl_xor(a00, 16);
    float p01 = a01 + __shfl_xor(a01, 16);
    float p10 = a10 + __shfl_xor(a10, 16);
    float p11 = a11 + __shfl_xor(a11, 16);
    float q00 = __shfl_xor(p00, 32), q01 = __shfl_xor(p01, 32);
    float q10 = __shfl_xor(p10, 32), q11 = __shfl_xor(p11, 32);
    bool hi = (tid >> 5) & 1u;
    float ya0 = p00 + q00, yd0 = hi ? (q00 - p00) : (p00 - q00);
    float ya1 = p01 + q01, yd1 = hi ? (q01 - p01) : (p01 - q01);
    float za0 = p10 + q10, zd0 = hi ? (q10 - p10) : (p10 - q10);
    float za1 = p11 + q11, zd1 = hi ? (q11 - p11) : (p11 - q11);
    if (((tid >> 4) & 3u) == 0u) {
      unsigned py = q * 4 + (tid >> 6);
      float* smp = sm + py * 17u + z4;
      smp[0 * 272] = (ya0 + ya1) * 0.125f;   // k=000
      smp[1 * 272] = (ya0 - ya1) * 0.125f;   // 001
      smp[2 * 272] = (yd0 + yd1) * 0.125f;   // 010
      smp[3 * 272] = (yd0 - yd1) * 0.125f;   // 011
      smp[4 * 272] = (za0 + za1) * 0.125f;   // 100
      smp[5 * 272] = (za0 - za1) * 0.125f;   // 101
      smp[6 * 272] = (zd0 + zd1) * 0.125f;   // 110
      smp[7 * 272] = (zd0 - zd1) * 0.125f;   // 111
    }
  }
  __syncthreads();
  if (tid < 128u) {  // z-DFT: thread = (k, ny)
    unsigned k = tid >> 4, y = tid & 15u;
    const float* row = sm + k * 272u + y * 17u;
#pragma unroll
    for (int kz = 0; kz < 3; kz++) {
      float re = 0.f, im = 0.f;
#pragma unroll
      for (int nz = 0; nz < 16; nz++) {
        float vv = row[nz];
        int t16 = (kz * nz) & 15;
        re += vv * C16c[t16];
        im -= vv * S16c[t16];
      }
      fz[k * 51u + kz * 17u + y] = make_float2(re, im);
    }
  }
  __syncthreads();
  if (tid < 144u) {  // y-DFT -> g2[b][row][px][c]
    unsigned k = tid / 18u, r = tid - k * 18u;
    unsigned kyi = r / 3u, kz = r - kyi * 3u;
    int ky = KYv[kyi];
    float re = 0.f, im = 0.f;
#pragma unroll
    for (int ny = 0; ny < 16; ny++) {
      float2 vv = fz[k * 51u + kz * 17u + ny];
      int t16 = (ky * ny) & 15;
      float cc = C16c[t16], sn = S16c[t16];
      re += vv.x * cc + vv.y * sn;
      im += vv.y * cc - vv.x * sn;
    }
    g2[(((size_t)b * 144u + tid) * 16u + px) * 64u + c] = make_float2(re, im);
  }
}

// ---------------------------------------------------------------------------
// K2: x-DFT (in-LDS, per-corner) + channel mix reading w directly (NT).
// WG = (kc = k*4+corner, ob in 8); handles the 2 batches of this half.
__global__ __launch_bounds__(256) void k2_mix(const float* __restrict__ w2,
                                              const float2* __restrict__ g2,
                                              float2* __restrict__ oh2,
                                              int half) {
  __shared__ float2 ihl[2][64][27];   // [b2][i=c][f]  27648 B
  unsigned tid = threadIdx.x;
  unsigned kc = blockIdx.x >> 3;
  unsigned ob = blockIdx.x & 7u;
  unsigned k = kc >> 2, corner = kc & 3u;
  unsigned kxi0 = 3u * (corner & 1u), kyi0 = 3u * (corner >> 1);
  if (tid < 128u) {  // prologue: thread = (b2, c)
    unsigned c = tid & 63u, b2 = tid >> 6;
    unsigned b = (unsigned)half * 2u + b2;
    const float2* gb = g2 + ((size_t)b * 144u * 16u) * 64u + c;
#pragma unroll
    for (unsigned kyl = 0; kyl < 3u; kyl++) {
#pragma unroll
      for (unsigned kz = 0; kz < 3u; kz++) {
        unsigned row = k * 18u + (kyl + kyi0) * 3u + kz;
        float2 rg[16];
#pragma unroll
        for (int nx = 0; nx < 16; nx++) rg[nx] = gb[((size_t)row * 16u + nx) * 64u];
#pragma unroll
        for (unsigned kxl = 0; kxl < 3u; kxl++) {
          int kx = KYv[kxl + kxi0];
          float re = 0.f, im = 0.f;
#pragma unroll
          for (int nx = 0; nx < 16; nx++) {
            int t16 = (kx * nx) & 15;
            float cc = C16c[t16], sn = S16c[t16];
            re += rg[nx].x * cc + rg[nx].y * sn;
            im += rg[nx].y * cc - rg[nx].x * sn;
          }
          ihl[b2][c][kxl * 9u + kyl * 3u + kz] = make_float2(re, im);
        }
      }
    }
  }
  __syncthreads();
  if (tid >= 216u) return;
  unsigned o = tid / 27u, f = tid - o * 27u;  // o in [0,8), f in [0,27)
  // w2 float layout: [kc][i][o64][f27][2]
  const float* wp = w2 + (((size_t)kc * 64u * 64u + (ob * 8u + o)) * 27u + f) * 2u;
  float2 acc[2];
#pragma unroll
  for (int b2 = 0; b2 < 2; b2++) acc[b2] = make_float2(0.f, 0.f);
#pragma unroll 8
  for (unsigned i = 0; i < 64u; i++) {
    float wr = __builtin_nontemporal_load(wp + (size_t)i * 3456u);
    float wi = __builtin_nontemporal_load(wp + (size_t)i * 3456u + 1u);
#pragma unroll
    for (int b2 = 0; b2 < 2; b2++) {
      float2 a = ihl[b2][i][f];
      acc[b2].x += a.x * wr - a.y * wi;
      acc[b2].y += a.x * wi + a.y * wr;
    }
  }
  unsigned kxl = f / 9u, kyl = (f - kxl * 9u) / 3u, kz = f % 3u;
  unsigned fg = (kxl + kxi0) * 18u + (kyl + kyi0) * 3u + kz;
#pragma unroll
  for (int b2 = 0; b2 < 2; b2++) {
    unsigned b = (unsigned)half * 2u + (unsigned)b2;
    oh2[((size_t)(b * 64u + ob * 8u + o)) * 864u + k * 108u + fg] = acc[b2];
  }
}

// ---------------------------------------------------------------------------
// K3: fused inverse sparse DFT + synthesis for one half. WG = (bo_local
// reversed, slab-pair). Normal x loads (LLC-resident from K1); NT out.
__global__ __launch_bounds__(256) void k3_invsynth(const float2* __restrict__ oh2,
                                                   const float* __restrict__ x,
                                                   float* __restrict__ out,
                                                   int half) {
  __shared__ float2 hh[864];          // [k][fg]
  __shared__ float2 gx[2][8][18];     // [sl][k][kyi*3+kz]
  __shared__ float2 uu[2][8][3][16];  // [sl][k][kz][ny]
  __shared__ float W[2][8][16][16];   // [sl][m][ny][nz]
  unsigned tid = threadIdx.x;
  unsigned sp = blockIdx.x & 7u;      // slab pair: nx = sp*2 + sl
  unsigned bo = (unsigned)half * 128u + (127u - (blockIdx.x >> 3));  // reversed
  for (unsigned i = tid; i < 864u; i += 256u)
    hh[i] = oh2[(size_t)bo * 864u + i];
  __syncthreads();
  for (unsigned i = tid; i < 288u; i += 256u) {  // x-inverse (both slabs)
    unsigned sl = i / 144u, j = i - sl * 144u;
    unsigned k = j / 18u, r = j - k * 18u;
    unsigned nx = sp * 2u + sl;
    float re = 0.f, im = 0.f;
#pragma unroll
    for (int kxi = 0; kxi < 6; kxi++) {
      float2 v = hh[k * 108u + kxi * 18 + r];
      int t16 = (KYv[kxi] * (int)nx) & 15;
      float cc = C16c[t16], sn = S16c[t16];
      re += v.x * cc - v.y * sn;
      im += v.x * sn + v.y * cc;
    }
    gx[sl][k][r] = make_float2(re, im);
  }
  __syncthreads();
  for (unsigned i = tid; i < 768u; i += 256u) {  // y-inverse
    unsigned sl = i / 384u, j = i - sl * 384u;
    unsigned k = j / 48u, rem = j - k * 48u;
    unsigned kz = rem >> 4, ny = rem & 15u;
    float re = 0.f, im = 0.f;
#pragma unroll
    for (int kyi = 0; kyi < 6; kyi++) {
      float2 v = gx[sl][k][kyi * 3 + kz];
      int t16 = (KYv[kyi] * (int)ny) & 15;
      float cc = C16c[t16], sn = S16c[t16];
      re += v.x * cc - v.y * sn;
      im += v.x * sn + v.y * cc;
    }
    uu[sl][k][kz][ny] = make_float2(re, im);
  }
  __syncthreads();
  for (unsigned i = tid; i < 512u; i += 256u) {  // z-inverse + Hadamard
    unsigned sl = i >> 8, ny = (i >> 4) & 15u, nz = i & 15u;
    float c1 = C16c[nz], s1 = S16c[nz];
    int t2 = (2 * nz) & 15;
    float c2 = C16c[t2], s2 = S16c[t2];
    float val[8];
#pragma unroll
    for (int k = 0; k < 8; k++) {
      float2 u0 = uu[sl][k][0][ny], u1 = uu[sl][k][1][ny], u2 = uu[sl][k][2][ny];
      val[k] = (u0.x + 2.f * (u1.x * c1 - u1.y * s1) + 2.f * (u2.x * c2 - u2.y * s2)) * (1.f / 4096.f);
    }
#pragma unroll
    for (int st = 1; st < 8; st <<= 1)
#pragma unroll
      for (int i2 = 0; i2 < 8; i2++)
        if (!(i2 & st)) {
          float a = val[i2], bb = val[i2 | st];
          val[i2] = a + bb;
          val[i2 | st] = a - bb;
        }
#pragma unroll
    for (int m = 0; m < 8; m++) W[sl][m][ny][nz] = val[m];
  }
  __syncthreads();
  unsigned w = tid >> 6, l = tid & 63u;
  unsigned z4 = l & 15u, y2 = l >> 4;
  unsigned mmy = ((y2 >> 1) & 1u) << 1;
  const float* xp = x + ((size_t)bo << 18);
  float* op = out + ((size_t)bo << 18);
#pragma unroll
  for (unsigned sl = 0; sl < 2u; ++sl) {
#pragma unroll
    for (unsigned r2 = 0; r2 < 8u; ++r2) {
      unsigned xp2 = r2 & 1u, yg = r2 >> 1;
      unsigned X0 = ((sp * 2u + sl) << 2) + (xp2 << 1);
      unsigned Y = (yg << 4) + (w << 2) + y2;
      size_t off = ((size_t)X0 << 12) + (Y << 6) + (z4 << 2);
      f32x4 v0 = *(const f32x4*)(xp + off);
      f32x4 v1 = *(const f32x4*)(xp + off + 4096u);
      float h0 = v0.x + v0.y + v1.x + v1.y;
      float h1 = v0.z + v0.w + v1.z + v1.w;
      float m0 = (h0 + __shfl_xor(h0, 16)) * 0.125f;
      float m1 = (h1 + __shfl_xor(h1, 16)) * 0.125f;
      unsigned ny = (yg << 2) + w;
      unsigned mm = (xp2 << 2) | mmy;
      float c0 = 0.125f * W[sl][mm][ny][z4] - m0;
      float c1 = 0.125f * W[sl][mm | 1u][ny][z4] - m1;
      v0.x += c0; v0.y += c0; v0.z += c1; v0.w += c1;
      v1.x += c0; v1.y += c0; v1.z += c1; v1.w += c1;
      __builtin_nontemporal_store(v0, (f32x4*)(op + off));
      __builtin_nontemporal_store(v1, (f32x4*)(op + off + 4096u));
    }
  }
}

extern "C" void kernel_launch(void* const* d_in, const int* in_sizes, int n_in,
                              void* d_out, int out_size, void* d_ws, size_t ws_size,
                              hipStream_t stream) {
  const float* x = (const float*)d_in[0];
  const float* w = (const float*)d_in[1];
  float* out = (float*)d_out;

  const size_t G_B = 4ull * 144 * 16 * 64 * 8;   // 4.72 MB
  const size_t OH_B = 256ull * 864 * 8;          // 1.77 MB

  float2 *g2, *oh2;
  char* ws = (char*)d_ws;
  if (ws_size >= G_B + OH_B) {
    g2 = (float2*)ws;
    oh2 = (float2*)(ws + G_B);
  } else {
    // oh2 must survive K2(h)->K3(h) -> ws (1.77 MB). g2 parks at the tail of
    // d_out (inside out[b=3]): its last reader is K2(h=1); K3(h=1) overwrites
    // that region only afterwards.
    oh2 = (float2*)ws;
    g2 = (float2*)((char*)d_out + (size_t)out_size * 4 - G_B);
  }

  for (int half = 0; half < 2; ++half) {
    k1_front<<<2048, 256, 0, stream>>>(x, g2, half);
    k2_mix<<<256, 256, 0, stream>>>(w, g2, oh2, half);
    k3_invsynth<<<1024, 256, 0, stream>>>(oh2, x, out, half);
  }
}

// Round 12
// 155.188 us; speedup vs baseline: 1.1938x; 1.1938x over previous
//
#include <hip/hip_runtime.h>

// WaveConv3d, reduced form:
//   s_k  = signed 4x4x4 block-reduce of x  (8 subbands, 16^3 per (b,c))
//   ih   = sparse 3D DFT of s_k (6x6x3 freqs)
//   oh   = per-frequency 64->64 channel mix
//   out  = x - mean_{2x2x2}(x) + (1/8) sum_k sign_k(cell) * idft(oh_k)
// K1 = analyze + z/y-DFT -> g2.  K2 = per-(kc,o-block) WG: in-LDS x-DFT of
// its corner's 27 freqs, then GEMM over i reading w DIRECTLY (original
// layout, NT, read exactly once).  K3 = inverse DFT + synthesis (normal x
// loads; NT out stores).  [R9 structure — best verified at 154.9 µs.
// LLC-retention variants R8/R10/R11 all regressed; reverted.]

typedef float f32x4 __attribute__((ext_vector_type(4)));

__constant__ float C16c[16] = {
  1.0f, 0.92387953251128675f, 0.70710678118654752f, 0.38268343236508977f,
  0.0f, -0.38268343236508977f, -0.70710678118654752f, -0.92387953251128675f,
  -1.0f, -0.92387953251128675f, -0.70710678118654752f, -0.38268343236508977f,
  0.0f, 0.38268343236508977f, 0.70710678118654752f, 0.92387953251128675f
};
__constant__ float S16c[16] = {
  0.0f, 0.38268343236508977f, 0.70710678118654752f, 0.92387953251128675f,
  1.0f, 0.92387953251128675f, 0.70710678118654752f, 0.38268343236508977f,
  0.0f, -0.38268343236508977f, -0.70710678118654752f, -0.92387953251128675f,
  -1.0f, -0.92387953251128675f, -0.70710678118654752f, -0.38268343236508977f
};
__constant__ int KYv[6] = {0, 1, 2, 13, 14, 15};

// ---------------------------------------------------------------------------
// K1: fused analyze + z-DFT + y-DFT. WG = (bc, px).
// g2 layout: [b][row 144][px 16][c 64], row = k*18 + kyi*3 + kz.
__global__ __launch_bounds__(256) void k1_front(const float* __restrict__ x,
                                                float2* __restrict__ g2) {
  __shared__ float sm[8 * 272 + 8];   // [k][py][pz(17)]
  __shared__ float2 fz[8 * 51];       // [k][kz][ny(17)]
  unsigned tid = threadIdx.x;
  unsigned px = blockIdx.x & 15u;
  unsigned bc = blockIdx.x >> 4;
  unsigned c = bc & 63u, b = bc >> 6;
  const f32x4* xp4 = (const f32x4*)(x + ((size_t)bc << 18)) + (size_t)px * 4096u;
  unsigned z4 = tid & 15u;
#pragma unroll
  for (int q = 0; q < 4; q++) {
    float a00 = 0.f, a01 = 0.f, a10 = 0.f, a11 = 0.f;  // [dx][zhalf]
#pragma unroll
    for (int i = 0; i < 4; i++) {
      f32x4 v = xp4[i * 1024 + q * 256 + tid];
      float h0 = v.x + v.y, h1 = v.z + v.w;
      a00 += h0; a01 += h1;
      if (i < 2) { a10 += h0; a11 += h1; } else { a10 -= h0; a11 -= h1; }
    }
    float p00 = a00 + __shfl_xor(a00, 16);
    float p01 = a01 + __shfl_xor(a01, 16);
    float p10 = a10 + __shfl_xor(a10, 16);
    float p11 = a11 + __shfl_xor(a11, 16);
    float q00 = __shfl_xor(p00, 32), q01 = __shfl_xor(p01, 32);
    float q10 = __shfl_xor(p10, 32), q11 = __shfl_xor(p11, 32);
    bool hi = (tid >> 5) & 1u;
    float ya0 = p00 + q00, yd0 = hi ? (q00 - p00) : (p00 - q00);
    float ya1 = p01 + q01, yd1 = hi ? (q01 - p01) : (p01 - q01);
    float za0 = p10 + q10, zd0 = hi ? (q10 - p10) : (p10 - q10);
    float za1 = p11 + q11, zd1 = hi ? (q11 - p11) : (p11 - q11);
    if (((tid >> 4) & 3u) == 0u) {
      unsigned py = q * 4 + (tid >> 6);
      float* smp = sm + py * 17u + z4;
      smp[0 * 272] = (ya0 + ya1) * 0.125f;   // k=000
      smp[1 * 272] = (ya0 - ya1) * 0.125f;   // 001
      smp[2 * 272] = (yd0 + yd1) * 0.125f;   // 010
      smp[3 * 272] = (yd0 - yd1) * 0.125f;   // 011
      smp[4 * 272] = (za0 + za1) * 0.125f;   // 100
      smp[5 * 272] = (za0 - za1) * 0.125f;   // 101
      smp[6 * 272] = (zd0 + zd1) * 0.125f;   // 110
      smp[7 * 272] = (zd0 - zd1) * 0.125f;   // 111
    }
  }
  __syncthreads();
  if (tid < 128u) {  // z-DFT: thread = (k, ny)
    unsigned k = tid >> 4, y = tid & 15u;
    const float* row = sm + k * 272u + y * 17u;
#pragma unroll
    for (int kz = 0; kz < 3; kz++) {
      float re = 0.f, im = 0.f;
#pragma unroll
      for (int nz = 0; nz < 16; nz++) {
        float vv = row[nz];
        int t16 = (kz * nz) & 15;
        re += vv * C16c[t16];
        im -= vv * S16c[t16];
      }
      fz[k * 51u + kz * 17u + y] = make_float2(re, im);
    }
  }
  __syncthreads();
  if (tid < 144u) {  // y-DFT -> g2[b][row][px][c]
    unsigned k = tid / 18u, r = tid - k * 18u;
    unsigned kyi = r / 3u, kz = r - kyi * 3u;
    int ky = KYv[kyi];
    float re = 0.f, im = 0.f;
#pragma unroll
    for (int ny = 0; ny < 16; ny++) {
      float2 vv = fz[k * 51u + kz * 17u + ny];
      int t16 = (ky * ny) & 15;
      float cc = C16c[t16], sn = S16c[t16];
      re += vv.x * cc + vv.y * sn;
      im += vv.y * cc - vv.x * sn;
    }
    g2[(((size_t)b * 144u + tid) * 16u + px) * 64u + c] = make_float2(re, im);
  }
}

// ---------------------------------------------------------------------------
// K2: x-DFT (in-LDS, per-corner) + channel mix reading w directly.
__global__ __launch_bounds__(256) void k2_mix(const float* __restrict__ w2,
                                              const float2* __restrict__ g2,
                                              float2* __restrict__ oh2) {
  __shared__ float2 ihl[4][64][27];   // [b][i=c][f]  55296 B
  unsigned tid = threadIdx.x;
  unsigned kc = blockIdx.x >> 3;
  unsigned ob = blockIdx.x & 7u;
  unsigned k = kc >> 2, corner = kc & 3u;
  unsigned kxi0 = 3u * (corner & 1u), kyi0 = 3u * (corner >> 1);
  {  // prologue: thread = (b, c)
    unsigned c = tid & 63u, b = tid >> 6;
    const float2* gb = g2 + ((size_t)b * 144u * 16u) * 64u + c;
#pragma unroll
    for (unsigned kyl = 0; kyl < 3u; kyl++) {
#pragma unroll
      for (unsigned kz = 0; kz < 3u; kz++) {
        unsigned row = k * 18u + (kyl + kyi0) * 3u + kz;
        float2 rg[16];
#pragma unroll
        for (int nx = 0; nx < 16; nx++) rg[nx] = gb[((size_t)row * 16u + nx) * 64u];
#pragma unroll
        for (unsigned kxl = 0; kxl < 3u; kxl++) {
          int kx = KYv[kxl + kxi0];
          float re = 0.f, im = 0.f;
#pragma unroll
          for (int nx = 0; nx < 16; nx++) {
            int t16 = (kx * nx) & 15;
            float cc = C16c[t16], sn = S16c[t16];
            re += rg[nx].x * cc + rg[nx].y * sn;
            im += rg[nx].y * cc - rg[nx].x * sn;
          }
          ihl[b][c][kxl * 9u + kyl * 3u + kz] = make_float2(re, im);
        }
      }
    }
  }
  __syncthreads();
  if (tid >= 216u) return;
  unsigned o = tid / 27u, f = tid - o * 27u;  // o in [0,8), f in [0,27)
  const float* wp = w2 + (((size_t)kc * 64u * 64u + (ob * 8u + o)) * 27u + f) * 2u;
  float2 acc[4];
#pragma unroll
  for (int b = 0; b < 4; b++) acc[b] = make_float2(0.f, 0.f);
#pragma unroll 8
  for (unsigned i = 0; i < 64u; i++) {
    float wr = __builtin_nontemporal_load(wp + (size_t)i * 3456u);
    float wi = __builtin_nontemporal_load(wp + (size_t)i * 3456u + 1u);
#pragma unroll
    for (int b = 0; b < 4; b++) {
      float2 a = ihl[b][i][f];
      acc[b].x += a.x * wr - a.y * wi;
      acc[b].y += a.x * wi + a.y * wr;
    }
  }
  unsigned kxl = f / 9u, kyl = (f - kxl * 9u) / 3u, kz = f % 3u;
  unsigned fg = (kxl + kxi0) * 18u + (kyl + kyi0) * 3u + kz;
#pragma unroll
  for (int b = 0; b < 4; b++)
    oh2[((size_t)(b * 64u + ob * 8u + o)) * 864u + k * 108u + fg] = acc[b];
}

// ---------------------------------------------------------------------------
// K3: fused inverse sparse DFT + synthesis. WG = (bo reversed, slab-pair).
// Normal x loads; NT out stores.
__global__ __launch_bounds__(256) void k3_invsynth(const float2* __restrict__ oh2,
                                                   const float* __restrict__ x,
                                                   float* __restrict__ out) {
  __shared__ float2 hh[864];          // [k][fg]
  __shared__ float2 gx[2][8][18];     // [sl][k][kyi*3+kz]
  __shared__ float2 uu[2][8][3][16];  // [sl][k][kz][ny]
  __shared__ float W[2][8][16][16];   // [sl][m][ny][nz]
  unsigned tid = threadIdx.x;
  unsigned sp = blockIdx.x & 7u;              // slab pair: nx = sp*2 + sl
  unsigned bo = 255u - (blockIdx.x >> 3);     // reversed
  for (unsigned i = tid; i < 864u; i += 256u)
    hh[i] = oh2[(size_t)bo * 864u + i];
  __syncthreads();
  for (unsigned i = tid; i < 288u; i += 256u) {  // x-inverse (both slabs)
    unsigned sl = i / 144u, j = i - sl * 144u;
    unsigned k = j / 18u, r = j - k * 18u;
    unsigned nx = sp * 2u + sl;
    float re = 0.f, im = 0.f;
#pragma unroll
    for (int kxi = 0; kxi < 6; kxi++) {
      float2 v = hh[k * 108u + kxi * 18 + r];
      int t16 = (KYv[kxi] * (int)nx) & 15;
      float cc = C16c[t16], sn = S16c[t16];
      re += v.x * cc - v.y * sn;
      im += v.x * sn + v.y * cc;
    }
    gx[sl][k][r] = make_float2(re, im);
  }
  __syncthreads();
  for (unsigned i = tid; i < 768u; i += 256u) {  // y-inverse
    unsigned sl = i / 384u, j = i - sl * 384u;
    unsigned k = j / 48u, rem = j - k * 48u;
    unsigned kz = rem >> 4, ny = rem & 15u;
    float re = 0.f, im = 0.f;
#pragma unroll
    for (int kyi = 0; kyi < 6; kyi++) {
      float2 v = gx[sl][k][kyi * 3 + kz];
      int t16 = (KYv[kyi] * (int)ny) & 15;
      float cc = C16c[t16], sn = S16c[t16];
      re += v.x * cc - v.y * sn;
      im += v.x * sn + v.y * cc;
    }
    uu[sl][k][kz][ny] = make_float2(re, im);
  }
  __syncthreads();
  for (unsigned i = tid; i < 512u; i += 256u) {  // z-inverse + Hadamard
    unsigned sl = i >> 8, ny = (i >> 4) & 15u, nz = i & 15u;
    float c1 = C16c[nz], s1 = S16c[nz];
    int t2 = (2 * nz) & 15;
    float c2 = C16c[t2], s2 = S16c[t2];
    float val[8];
#pragma unroll
    for (int k = 0; k < 8; k++) {
      float2 u0 = uu[sl][k][0][ny], u1 = uu[sl][k][1][ny], u2 = uu[sl][k][2][ny];
      val[k] = (u0.x + 2.f * (u1.x * c1 - u1.y * s1) + 2.f * (u2.x * c2 - u2.y * s2)) * (1.f / 4096.f);
    }
#pragma unroll
    for (int st = 1; st < 8; st <<= 1)
#pragma unroll
      for (int i2 = 0; i2 < 8; i2++)
        if (!(i2 & st)) {
          float a = val[i2], bb = val[i2 | st];
          val[i2] = a + bb;
          val[i2 | st] = a - bb;
        }
#pragma unroll
    for (int m = 0; m < 8; m++) W[sl][m][ny][nz] = val[m];
  }
  __syncthreads();
  unsigned w = tid >> 6, l = tid & 63u;
  unsigned z4 = l & 15u, y2 = l >> 4;
  unsigned mmy = ((y2 >> 1) & 1u) << 1;
  const float* xp = x + ((size_t)bo << 18);
  float* op = out + ((size_t)bo << 18);
#pragma unroll
  for (unsigned sl = 0; sl < 2u; ++sl) {
#pragma unroll
    for (unsigned r2 = 0; r2 < 8u; ++r2) {
      unsigned xp2 = r2 & 1u, yg = r2 >> 1;
      unsigned X0 = ((sp * 2u + sl) << 2) + (xp2 << 1);
      unsigned Y = (yg << 4) + (w << 2) + y2;
      size_t off = ((size_t)X0 << 12) + (Y << 6) + (z4 << 2);
      f32x4 v0 = *(const f32x4*)(xp + off);
      f32x4 v1 = *(const f32x4*)(xp + off + 4096u);
      float h0 = v0.x + v0.y + v1.x + v1.y;
      float h1 = v0.z + v0.w + v1.z + v1.w;
      float m0 = (h0 + __shfl_xor(h0, 16)) * 0.125f;
      float m1 = (h1 + __shfl_xor(h1, 16)) * 0.125f;
      unsigned ny = (yg << 2) + w;
      unsigned mm = (xp2 << 2) | mmy;
      float c0 = 0.125f * W[sl][mm][ny][z4] - m0;
      float c1 = 0.125f * W[sl][mm | 1u][ny][z4] - m1;
      v0.x += c0; v0.y += c0; v0.z += c1; v0.w += c1;
      v1.x += c0; v1.y += c0; v1.z += c1; v1.w += c1;
      __builtin_nontemporal_store(v0, (f32x4*)(op + off));
      __builtin_nontemporal_store(v1, (f32x4*)(op + off + 4096u));
    }
  }
}

extern "C" void kernel_launch(void* const* d_in, const int* in_sizes, int n_in,
                              void* d_out, int out_size, void* d_ws, size_t ws_size,
                              hipStream_t stream) {
  const float* x = (const float*)d_in[0];
  const float* w = (const float*)d_in[1];
  float* out = (float*)d_out;

  const size_t G_B = 4ull * 144 * 16 * 64 * 8;   // 4.72 MB
  const size_t OH_B = 256ull * 864 * 8;          // 1.77 MB

  float2 *g2, *oh2;
  char* ws = (char*)d_ws;
  if (ws_size >= G_B + OH_B) {
    g2 = (float2*)ws;
    oh2 = (float2*)(ws + G_B);
  } else {
    // oh2 must survive into K3 -> ws (1.77 MB). g2 is dead after K2; park it
    // at the tail of d_out (K3 overwrites it only after K2 completed).
    oh2 = (float2*)ws;
    g2 = (float2*)((char*)d_out + (size_t)out_size * 4 - G_B);
  }

  k1_front<<<4096, 256, 0, stream>>>(x, g2);
  k2_mix<<<256, 256, 0, stream>>>(w, g2, oh2);
  k3_invsynth<<<2048, 256, 0, stream>>>(oh2, x, out);
}